// Round 1
// baseline (1343.740 us; speedup 1.0000x reference)
//
#include <hip/hip_runtime.h>
#include <hip/hip_bf16.h>
#include <cstddef>
#include <cstdint>

#define BS 32768
#define MSLOT 2048
#define D 256

// ---------------------------------------------------------------- normalize
__global__ __launch_bounds__(256) void k_normalize(const float* __restrict__ query,
                                                   float* __restrict__ q,
                                                   float* __restrict__ out0)
{
    __shared__ float sbuf[4];
    const int i = blockIdx.x, t = threadIdx.x;
    float v = query[(size_t)i * D + t];
    float ss = v * v;
#pragma unroll
    for (int off = 32; off; off >>= 1) ss += __shfl_xor(ss, off, 64);
    if ((t & 63) == 0) sbuf[t >> 6] = ss;
    __syncthreads();
    float tot = (sbuf[0] + sbuf[1]) + (sbuf[2] + sbuf[3]);
    float n = fmaxf(sqrtf(tot), 1e-12f);
    float qv = v / n;
    q[(size_t)i * D + t] = qv;
    out0[(size_t)i * (2 * D) + t] = qv;
}

// ---------------------------------------------------------------- f32 GEMM
// C[M x N] = A[M x K] * op(B);  BT=true: B is [N x K] row-major (C=A*B^T)
//                               BT=false: B is [K x N] row-major (C=A*B)
template <bool BT>
__global__ __launch_bounds__(256) void gemm128(const float* __restrict__ A,
                                               const float* __restrict__ B,
                                               float* __restrict__ C,
                                               int K, int lda, int ldb, int ldc)
{
    constexpr int BM = 128, BN = 128, BK = 16;
    __shared__ float As[BK][BM + 4];
    __shared__ float Bs[BK][BN + 4];
    const int tid = threadIdx.x;
    const int i0 = blockIdx.y * BM;
    const int j0 = blockIdx.x * BN;
    const int tx4 = (tid & 15) * 4;
    const int ty4 = (tid >> 4) * 4;
    float acc[8][8] = {};

    for (int k0 = 0; k0 < K; k0 += BK) {
#pragma unroll
        for (int l = 0; l < 2; ++l) {
            int f = tid + l * 256;
            {
                int row = f >> 2, cc = (f & 3) * 4;
                float4 a = *(const float4*)(A + (size_t)(i0 + row) * lda + k0 + cc);
                As[cc + 0][row] = a.x; As[cc + 1][row] = a.y;
                As[cc + 2][row] = a.z; As[cc + 3][row] = a.w;
            }
            if constexpr (BT) {
                int row = f >> 2, cc = (f & 3) * 4;
                float4 b = *(const float4*)(B + (size_t)(j0 + row) * ldb + k0 + cc);
                Bs[cc + 0][row] = b.x; Bs[cc + 1][row] = b.y;
                Bs[cc + 2][row] = b.z; Bs[cc + 3][row] = b.w;
            } else {
                int kr = f >> 5, cc = (f & 31) * 4;
                float4 b = *(const float4*)(B + (size_t)(k0 + kr) * ldb + j0 + cc);
                *(float4*)&Bs[kr][cc] = b;
            }
        }
        __syncthreads();
#pragma unroll
        for (int kk = 0; kk < BK; ++kk) {
            float4 a0 = *(const float4*)&As[kk][ty4];
            float4 a1 = *(const float4*)&As[kk][ty4 + 64];
            float4 b0 = *(const float4*)&Bs[kk][tx4];
            float4 b1 = *(const float4*)&Bs[kk][tx4 + 64];
            float av[8] = {a0.x, a0.y, a0.z, a0.w, a1.x, a1.y, a1.z, a1.w};
            float bv[8] = {b0.x, b0.y, b0.z, b0.w, b1.x, b1.y, b1.z, b1.w};
#pragma unroll
            for (int ii = 0; ii < 8; ++ii)
#pragma unroll
                for (int jj = 0; jj < 8; ++jj)
                    acc[ii][jj] += av[ii] * bv[jj];
        }
        __syncthreads();
    }
#pragma unroll
    for (int ii = 0; ii < 8; ++ii) {
        int r = i0 + ty4 + ((ii < 4) ? ii : ii + 60);
        float4 c0 = {acc[ii][0], acc[ii][1], acc[ii][2], acc[ii][3]};
        float4 c1 = {acc[ii][4], acc[ii][5], acc[ii][6], acc[ii][7]};
        *(float4*)(C + (size_t)r * ldc + j0 + tx4) = c0;
        *(float4*)(C + (size_t)r * ldc + j0 + tx4 + 64) = c1;
    }
}

// ---------------------------------------------------------------- column stats
#define ROWCHUNK 256
#define NCHUNK (BS / ROWCHUNK)

__global__ __launch_bounds__(256) void k_colstats(const float* __restrict__ score,
                                                  float* __restrict__ colpart)
{
    const int col = blockIdx.x * 256 + threadIdx.x;
    const int r0 = blockIdx.y * ROWCHUNK;
    float m = -INFINITY, s = 0.f;
    for (int r = r0; r < r0 + ROWCHUNK; ++r) {
        float v = score[(size_t)r * MSLOT + col];
        if (v > m) { s = s * __expf(m - v) + 1.f; m = v; }
        else       { s += __expf(v - m); }
    }
    size_t o = ((size_t)blockIdx.y * MSLOT + col) * 2;
    colpart[o + 0] = m;
    colpart[o + 1] = s;
}

__global__ __launch_bounds__(256) void k_colmerge(const float* __restrict__ colpart,
                                                  float* __restrict__ colM,
                                                  float* __restrict__ colSinv,
                                                  float* __restrict__ colC)
{
    const int col = blockIdx.x * 256 + threadIdx.x;
    float m = -INFINITY, s = 0.f;
    for (int c = 0; c < NCHUNK; ++c) {
        size_t o = ((size_t)c * MSLOT + col) * 2;
        float pm = colpart[o + 0], ps = colpart[o + 1];
        if (pm > m) { s = s * __expf(m - pm) + ps; m = pm; }
        else        { s += ps * __expf(pm - m); }
    }
    colM[col] = m;
    colSinv[col] = 1.f / s;
    colC[col] = m + __logf(s);
}

// ---------------------------------------------------------------- per-row pass
__global__ __launch_bounds__(256) void k_rowpass(const float* __restrict__ score,
                                                 const float* __restrict__ colM,
                                                 const float* __restrict__ colC,
                                                 const float* __restrict__ q,
                                                 const float* __restrict__ memory,
                                                 float* __restrict__ rmaxA,
                                                 float* __restrict__ rsinvA,
                                                 int* __restrict__ jstarA,
                                                 float* __restrict__ wA,
                                                 float* __restrict__ gpart,
                                                 float* __restrict__ spart)
{
    __shared__ float sf[256];
    __shared__ float sf2[256];
    __shared__ int   si[256];
    __shared__ int   si2[256];
    __shared__ int   btop2[2];

    const int i = blockIdx.x, t = threadIdx.x;
    const float* row = score + (size_t)i * MSLOT;
    float v[8];
#pragma unroll
    for (int k = 0; k < 8; ++k) v[k] = row[t + k * 256];

    // row max
    float lm = v[0];
#pragma unroll
    for (int k = 1; k < 8; ++k) lm = fmaxf(lm, v[k]);
    sf[t] = lm; __syncthreads();
    for (int off = 128; off; off >>= 1) { if (t < off) sf[t] = fmaxf(sf[t], sf[t + off]); __syncthreads(); }
    float rm = sf[0]; __syncthreads();

    // row sum exp
    float ls = 0.f;
#pragma unroll
    for (int k = 0; k < 8; ++k) ls += __expf(v[k] - rm);
    sf[t] = ls; __syncthreads();
    for (int off = 128; off; off >>= 1) { if (t < off) sf[t] += sf[t + off]; __syncthreads(); }
    float rs = sf[0]; __syncthreads();

    // top2 of raw score (ties -> smaller index, matching lax.top_k)
    float v0 = -INFINITY, v1 = -INFINITY;
    int   i0 = 0x7fffffff, i1 = 0x7fffffff;
#pragma unroll
    for (int k = 0; k < 8; ++k) {
        int idx = t + k * 256; float cv = v[k];
        if (cv > v0)      { v1 = v0; i1 = i0; v0 = cv; i0 = idx; }
        else if (cv > v1) { v1 = cv; i1 = idx; }
    }
    sf[t] = v0; si[t] = i0; sf2[t] = v1; si2[t] = i1; __syncthreads();
    for (int off = 128; off; off >>= 1) {
        if (t < off) {
            float a0 = sf[t],      a1 = sf2[t];      int ai0 = si[t],      ai1 = si2[t];
            float b0 = sf[t + off], b1 = sf2[t + off]; int bi0 = si[t + off], bi1 = si2[t + off];
            float n0, n1; int ni0, ni1;
            bool bt = (b0 > a0) || (b0 == a0 && bi0 < ai0);
            if (bt) {
                n0 = b0; ni0 = bi0;
                bool s2 = (b1 > a0) || (b1 == a0 && bi1 < ai0);
                n1 = s2 ? b1 : a0; ni1 = s2 ? bi1 : ai0;
            } else {
                n0 = a0; ni0 = ai0;
                bool s2 = (b0 > a1) || (b0 == a1 && bi0 < ai1);
                n1 = s2 ? b0 : a1; ni1 = s2 ? bi0 : ai1;
            }
            sf[t] = n0; si[t] = ni0; sf2[t] = n1; si2[t] = ni1;
        }
        __syncthreads();
    }
    if (t == 0) { btop2[0] = si[0]; btop2[1] = si2[0]; }
    __syncthreads();
    const int top0 = btop2[0], top1 = btop2[1];
    __syncthreads();

    // argmax_j of (score - C_j)  == argmax of column-softmax row
    float av = -INFINITY; int ai = 0x7fffffff;
#pragma unroll
    for (int k = 0; k < 8; ++k) {
        int idx = t + k * 256;
        float x = v[k] - colC[idx];
        if (x > av || (x == av && idx < ai)) { av = x; ai = idx; }
    }
    sf[t] = av; si[t] = ai; __syncthreads();
    for (int off = 128; off; off >>= 1) {
        if (t < off) {
            float b = sf[t + off]; int bidx = si[t + off];
            if (b > sf[t] || (b == sf[t] && bidx < si[t])) { sf[t] = b; si[t] = bidx; }
        }
        __syncthreads();
    }
    if (t == 0) {
        int j = si[0];
        jstarA[i] = j;
        wA[i]     = __expf(row[j] - colM[j]);   // sel / colmax
        rmaxA[i]  = rm;
        rsinvA[i] = 1.0f / rs;
    }

    // losses
    float qv = q[(size_t)i * D + t];
    float pv = memory[(size_t)top0 * D + t];
    float nv = memory[(size_t)top1 * D + t];
    float dq = qv - pv;
    float g  = dq * dq;
    float dp = dq + 1e-6f;        dp *= dp;
    float dn = (qv - nv) + 1e-6f; dn *= dn;

    __syncthreads(); sf[t] = g; __syncthreads();
    for (int off = 128; off; off >>= 1) { if (t < off) sf[t] += sf[t + off]; __syncthreads(); }
    float gsum = sf[0]; __syncthreads();
    sf[t] = dp; __syncthreads();
    for (int off = 128; off; off >>= 1) { if (t < off) sf[t] += sf[t + off]; __syncthreads(); }
    float dpsum = sf[0]; __syncthreads();
    sf[t] = dn; __syncthreads();
    for (int off = 128; off; off >>= 1) { if (t < off) sf[t] += sf[t + off]; __syncthreads(); }
    float dnsum = sf[0];
    if (t == 0) {
        gpart[i] = gsum;
        spart[i] = fmaxf(sqrtf(dpsum) - sqrtf(dnsum) + 1.0f, 0.0f);
    }
}

// ---------------------------------------------------------------- softmax transform (in place for sfxq)
__global__ __launch_bounds__(256) void k_transform(float* __restrict__ sq,
                                                   float* __restrict__ sm,
                                                   const float* __restrict__ colM,
                                                   const float* __restrict__ colSinv,
                                                   const float* __restrict__ rmaxA,
                                                   const float* __restrict__ rsinvA)
{
    size_t f4 = (size_t)blockIdx.x * 256 + threadIdx.x;
    size_t base = f4 * 4;
    int i = (int)(base >> 11);
    int j = (int)(base & (MSLOT - 1));
    float4 s = *(const float4*)(sq + base);
    float rm = rmaxA[i], ri = rsinvA[i];
    float4 oq, om;
    oq.x = __expf(s.x - colM[j + 0]) * colSinv[j + 0];
    oq.y = __expf(s.y - colM[j + 1]) * colSinv[j + 1];
    oq.z = __expf(s.z - colM[j + 2]) * colSinv[j + 2];
    oq.w = __expf(s.w - colM[j + 3]) * colSinv[j + 3];
    om.x = __expf(s.x - rm) * ri;
    om.y = __expf(s.y - rm) * ri;
    om.z = __expf(s.z - rm) * ri;
    om.w = __expf(s.w - rm) * ri;
    *(float4*)(sq + base) = oq;
    *(float4*)(sm + base) = om;
}

// ---------------------------------------------------------------- segment sum (atomic scatter)
__global__ __launch_bounds__(256) void k_scatter(const float* __restrict__ q,
                                                 const int* __restrict__ jstarA,
                                                 const float* __restrict__ wA,
                                                 float* __restrict__ qupd)
{
    const int i = blockIdx.x, t = threadIdx.x;
    const int j = jstarA[i];
    const float w = wA[i];
    unsafeAtomicAdd(&qupd[(size_t)j * D + t], w * q[(size_t)i * D + t]);
}

// ---------------------------------------------------------------- updated memory
__global__ __launch_bounds__(256) void k_updmem(const float* __restrict__ qupd,
                                                const float* __restrict__ memory,
                                                float* __restrict__ out1)
{
    __shared__ float sbuf[4];
    const int j = blockIdx.x, t = threadIdx.x;
    float v = qupd[(size_t)j * D + t] + memory[(size_t)j * D + t];
    float ss = v * v;
#pragma unroll
    for (int off = 32; off; off >>= 1) ss += __shfl_xor(ss, off, 64);
    if ((t & 63) == 0) sbuf[t >> 6] = ss;
    __syncthreads();
    float tot = (sbuf[0] + sbuf[1]) + (sbuf[2] + sbuf[3]);
    float n = fmaxf(sqrtf(tot), 1e-12f);
    out1[(size_t)j * D + t] = v / n;
}

// ---------------------------------------------------------------- loss reduce
__global__ __launch_bounds__(256) void k_losses(const float* __restrict__ gpart,
                                                const float* __restrict__ spart,
                                                float* __restrict__ out45)
{
    __shared__ float sf[256];
    const int t = threadIdx.x;
    float g = 0.f, s = 0.f;
    for (int i = t; i < BS; i += 256) { g += gpart[i]; s += spart[i]; }
    sf[t] = g; __syncthreads();
    for (int off = 128; off; off >>= 1) { if (t < off) sf[t] += sf[t + off]; __syncthreads(); }
    float gt = sf[0]; __syncthreads();
    sf[t] = s; __syncthreads();
    for (int off = 128; off; off >>= 1) { if (t < off) sf[t] += sf[t + off]; __syncthreads(); }
    float st = sf[0];
    if (t == 0) {
        out45[0] = gt / (float)((size_t)BS * D);
        out45[1] = st / (float)BS;
    }
}

// ---------------------------------------------------------------- launcher
extern "C" void kernel_launch(void* const* d_in, const int* in_sizes, int n_in,
                              void* d_out, int out_size, void* d_ws, size_t ws_size,
                              hipStream_t stream)
{
    const float* query  = (const float*)d_in[0];
    const float* memory = (const float*)d_in[1];

    float* out  = (float*)d_out;
    float* out0 = out;                                   // update_query  [BS][2D]
    float* out1 = out0 + (size_t)BS * 2 * D;             // updated_memory[M][D]
    float* out2 = out1 + (size_t)MSLOT * D;              // sfx_score_query [BS][M] (raw score first)
    float* out3 = out2 + (size_t)BS * MSLOT;             // sfx_score_memory[BS][M]
    float* out45 = out3 + (size_t)BS * MSLOT;            // two scalars

    float* ws      = (float*)d_ws;
    float* q       = ws;                                  // BS*D
    float* colpart = q + (size_t)BS * D;                  // NCHUNK*M*2
    float* colM    = colpart + (size_t)NCHUNK * MSLOT * 2;
    float* colSinv = colM + MSLOT;
    float* colC    = colSinv + MSLOT;
    float* rmaxA   = colC + MSLOT;                        // BS
    float* rsinvA  = rmaxA + BS;                          // BS
    float* wA      = rsinvA + BS;                         // BS
    int*   jstarA  = (int*)(wA + BS);                     // BS
    float* gpart   = (float*)(jstarA + BS);               // BS
    float* spart   = gpart + BS;                          // BS
    float* qupd    = spart + BS;                          // M*D

    // 1) q = normalize(query); also write into out0 left half
    k_normalize<<<BS, 256, 0, stream>>>(query, q, out0);

    // 2) raw score = q @ memory^T -> out2 (in place later)
    gemm128<true><<<dim3(MSLOT / 128, BS / 128), 256, 0, stream>>>(
        q, memory, out2, D, D, D, MSLOT);

    // 3) column stats (softmax over axis 0)
    k_colstats<<<dim3(MSLOT / 256, NCHUNK), 256, 0, stream>>>(out2, colpart);
    k_colmerge<<<MSLOT / 256, 256, 0, stream>>>(colpart, colM, colSinv, colC);

    // 4) per-row pass: row stats, top2, argmax, w, loss partials
    k_rowpass<<<BS, 256, 0, stream>>>(out2, colM, colC, q, memory,
                                      rmaxA, rsinvA, jstarA, wA, gpart, spart);

    // 5) elementwise softmax transforms: out2 -> sfxq (in place), out3 -> sfxm
    k_transform<<<(BS * (MSLOT / 4)) / 256, 256, 0, stream>>>(
        out2, out3, colM, colSinv, rmaxA, rsinvA);

    // 6) segment-sum memory update
    hipMemsetAsync(qupd, 0, (size_t)MSLOT * D * sizeof(float), stream);
    k_scatter<<<BS, 256, 0, stream>>>(q, jstarA, wA, qupd);
    k_updmem<<<MSLOT, 256, 0, stream>>>(qupd, memory, out1);

    // 7) concat_memory = sfxm @ memory -> out0 right half (ldc = 2D, offset D)
    gemm128<false><<<dim3(D / 128, BS / 128), 256, 0, stream>>>(
        out3, memory, out0 + D, MSLOT, MSLOT, D, 2 * D);

    // 8) losses
    k_losses<<<1, 256, 0, stream>>>(gpart, spart, out45);
}

// Round 2
// 612.412 us; speedup vs baseline: 2.1942x; 2.1942x over previous
//
#include <hip/hip_runtime.h>
#include <hip/hip_bf16.h>
#include <cstddef>
#include <cstdint>

#define BS 32768
#define MSLOT 2048
#define D 256
#define NCHUNK 256   // i-tiles of 128 rows in gemm1

typedef _Float16 f16;
typedef _Float16 f16x8 __attribute__((ext_vector_type(8)));
typedef float f32x4 __attribute__((ext_vector_type(4)));

__device__ __forceinline__ void lds_cp16(void* dst, const void* src) {
    __builtin_amdgcn_global_load_lds(
        (const __attribute__((address_space(1))) void*)src,
        (__attribute__((address_space(3))) void*)dst, 16, 0, 0);
}

__device__ __forceinline__ void top2_merge(float& a0, int& ai0, float& a1, int& ai1,
                                           float b0, int bi0, float b1, int bi1)
{
    bool bt = (b0 > a0) || (b0 == a0 && bi0 < ai0);
    float n0, n1; int ni0, ni1;
    if (bt) {
        n0 = b0; ni0 = bi0;
        bool s2 = (b1 > a0) || (b1 == a0 && bi1 < ai0);
        n1 = s2 ? b1 : a0; ni1 = s2 ? bi1 : ai0;
    } else {
        n0 = a0; ni0 = ai0;
        bool s2 = (b0 > a1) || (b0 == a1 && bi0 < ai1);
        n1 = s2 ? b0 : a1; ni1 = s2 ? bi0 : ai1;
    }
    a0 = n0; ai0 = ni0; a1 = n1; ai1 = ni1;
}

// ---------------------------------------------------------------- prep: normalize + f16x2 split (q scaled by 256)
__global__ __launch_bounds__(256) void k_prepq(const float* __restrict__ query,
                                               float* __restrict__ out0,
                                               f16* __restrict__ qh, f16* __restrict__ ql)
{
    __shared__ float sbuf[4];
    const int i = blockIdx.x, t = threadIdx.x;
    float v = query[(size_t)i * D + t];
    float ss = v * v;
#pragma unroll
    for (int off = 32; off; off >>= 1) ss += __shfl_xor(ss, off, 64);
    if ((t & 63) == 0) sbuf[t >> 6] = ss;
    __syncthreads();
    float tot = (sbuf[0] + sbuf[1]) + (sbuf[2] + sbuf[3]);
    float n = fmaxf(sqrtf(tot), 1e-12f);
    float qv = v / n;
    out0[(size_t)i * (2 * D) + t] = qv;
    float qs = qv * 256.0f;
    f16 h = (f16)qs;
    f16 lo = (f16)(qs - (float)h);
    qh[(size_t)i * D + t] = h;
    ql[(size_t)i * D + t] = lo;
}

// ---------------------------------------------------------------- prep: memory split + f16 transpose
__global__ __launch_bounds__(256) void k_prepm(const float* __restrict__ memory,
                                               f16* __restrict__ mh, f16* __restrict__ ml,
                                               f16* __restrict__ memT)
{
    const int j = blockIdx.x, t = threadIdx.x;
    float m = memory[(size_t)j * D + t];
    f16 h = (f16)m;
    f16 lo = (f16)(m - (float)h);
    mh[(size_t)j * D + t] = h;
    ml[(size_t)j * D + t] = lo;
    memT[(size_t)t * MSLOT + j] = h;   // [n=dim][k=slot]
}

// ---------------------------------------------------------------- score GEMM (f16x2, 3 products) + col partials
// score = q @ mem^T, scaled operands: acc ~ 256*score. grid (16 j-tiles, 256 i-tiles), 256 thr.
__global__ __launch_bounds__(256) void k_score(const f16* __restrict__ qh, const f16* __restrict__ ql,
                                               const f16* __restrict__ mh, const f16* __restrict__ ml,
                                               float* __restrict__ out2,
                                               float* __restrict__ colpart)
{
    __shared__ __align__(16) f16 Ah[4096], Al[4096], Bh[4096], Bl[4096];   // [128][32]
    __shared__ float sepM[4][4][16], sepS[4][4][16];
    const int t = threadIdx.x;
    const int l = t & 63, w = t >> 6;
    const int wr = w >> 1, wc = w & 1;
    const int lk = l >> 4, lm = l & 15;
    const int i0 = blockIdx.y * 128, j0 = blockIdx.x * 128;

    f32x4 acc[4][4] = {};

    for (int ks = 0; ks < 8; ++ks) {
        const int k0 = ks * 32;
#pragma unroll
        for (int c = 0; c < 2; ++c) {
            int s = c * 256 + t;
            int r = s >> 2, cc = s & 3;
            int scc = cc ^ ((r >> 1) & 3);          // pre-swizzled source chunk
            size_t aoff = (size_t)(i0 + r) * D + k0 + scc * 8;
            size_t boff = (size_t)(j0 + r) * D + k0 + scc * 8;
            lds_cp16(&Ah[s * 8], qh + aoff);
            lds_cp16(&Al[s * 8], ql + aoff);
            lds_cp16(&Bh[s * 8], mh + boff);
            lds_cp16(&Bl[s * 8], ml + boff);
        }
        __syncthreads();
        f16x8 a_h[4], a_l[4], b_h[4], b_l[4];
#pragma unroll
        for (int m = 0; m < 4; ++m) {
            int r = wr * 64 + m * 16 + lm;
            int off = r * 64 + ((lk ^ ((r >> 1) & 3)) << 4);
            a_h[m] = *(const f16x8*)((const char*)Ah + off);
            a_l[m] = *(const f16x8*)((const char*)Al + off);
        }
#pragma unroll
        for (int n = 0; n < 4; ++n) {
            int r = wc * 64 + n * 16 + lm;
            int off = r * 64 + ((lk ^ ((r >> 1) & 3)) << 4);
            b_h[n] = *(const f16x8*)((const char*)Bh + off);
            b_l[n] = *(const f16x8*)((const char*)Bl + off);
        }
#pragma unroll
        for (int m = 0; m < 4; ++m)
#pragma unroll
            for (int n = 0; n < 4; ++n) {
                acc[m][n] = __builtin_amdgcn_mfma_f32_16x16x32_f16(a_h[m], b_h[n], acc[m][n], 0, 0, 0);
                acc[m][n] = __builtin_amdgcn_mfma_f32_16x16x32_f16(a_h[m], b_l[n], acc[m][n], 0, 0, 0);
                acc[m][n] = __builtin_amdgcn_mfma_f32_16x16x32_f16(a_l[m], b_h[n], acc[m][n], 0, 0, 0);
            }
        __syncthreads();
    }

    // scale back (q was pre-scaled by 256)
    const float sc = 1.0f / 256.0f;
#pragma unroll
    for (int m = 0; m < 4; ++m)
#pragma unroll
        for (int n = 0; n < 4; ++n)
            acc[m][n] *= sc;

    // store raw score
#pragma unroll
    for (int m = 0; m < 4; ++m) {
        int row = i0 + wr * 64 + m * 16 + lk * 4;
#pragma unroll
        for (int n = 0; n < 4; ++n) {
            int col = j0 + wc * 64 + n * 16 + lm;
#pragma unroll
            for (int r = 0; r < 4; ++r)
                out2[(size_t)(row + r) * MSLOT + col] = acc[m][n][r];
        }
    }

    // fused column partials (online max+sumexp over this block's 128 rows)
    float cm[4], cs[4];
#pragma unroll
    for (int n = 0; n < 4; ++n) {
        float mx = -INFINITY;
#pragma unroll
        for (int m = 0; m < 4; ++m)
#pragma unroll
            for (int r = 0; r < 4; ++r) mx = fmaxf(mx, acc[m][n][r]);
        float sm = 0.0f;
#pragma unroll
        for (int m = 0; m < 4; ++m)
#pragma unroll
            for (int r = 0; r < 4; ++r) sm += __expf(acc[m][n][r] - mx);
        // merge across lane groups (rows): lanes differing in bits 4,5
#pragma unroll
        for (int off = 16; off <= 32; off <<= 1) {
            float om = __shfl_xor(mx, off, 64);
            float os = __shfl_xor(sm, off, 64);
            float nm = fmaxf(mx, om);
            sm = sm * __expf(mx - nm) + os * __expf(om - nm);
            mx = nm;
        }
        cm[n] = mx; cs[n] = sm;
    }
    if (l < 16) {
#pragma unroll
        for (int n = 0; n < 4; ++n) { sepM[w][n][l] = cm[n]; sepS[w][n][l] = cs[n]; }
    }
    __syncthreads();
    if (w < 2 && l < 16) {
#pragma unroll
        for (int n = 0; n < 4; ++n) {
            float m1 = sepM[w][n][l], s1 = sepS[w][n][l];
            float m2 = sepM[w + 2][n][l], s2 = sepS[w + 2][n][l];
            float nm = fmaxf(m1, m2);
            float ns = s1 * __expf(m1 - nm) + s2 * __expf(m2 - nm);
            int col = j0 + w * 64 + n * 16 + l;
            size_t o = ((size_t)blockIdx.y * MSLOT + col) * 2;
            colpart[o + 0] = nm;
            colpart[o + 1] = ns;
        }
    }
}

// ---------------------------------------------------------------- column merge
__global__ __launch_bounds__(256) void k_colmerge(const float* __restrict__ colpart,
                                                  float* __restrict__ colM,
                                                  float* __restrict__ colSinv,
                                                  float* __restrict__ colC)
{
    const int col = blockIdx.x * 256 + threadIdx.x;
    float m = -INFINITY, s = 0.0f;
    for (int c = 0; c < NCHUNK; ++c) {
        size_t o = ((size_t)c * MSLOT + col) * 2;
        float pm = colpart[o + 0], ps = colpart[o + 1];
        float nm = fmaxf(m, pm);
        s = s * __expf(m - nm) + ps * __expf(pm - nm);
        m = nm;
    }
    colM[col] = m;
    colSinv[col] = 1.0f / s;
    colC[col] = m + __logf(s);
}

// ---------------------------------------------------------------- fused row pass + softmax transforms
__global__ __launch_bounds__(256) void k_rowtrans(float* __restrict__ sq,   // out2 in-place
                                                  float* __restrict__ sm,   // out3
                                                  const float* __restrict__ colM,
                                                  const float* __restrict__ colSinv,
                                                  const float* __restrict__ colC,
                                                  const float* __restrict__ out0,   // q in left half, ld 2D
                                                  const float* __restrict__ memory,
                                                  int* __restrict__ jstarA, float* __restrict__ wA,
                                                  float* __restrict__ gpart, float* __restrict__ spart)
{
    __shared__ float swm[4], sws[4];
    __shared__ float st0v[4], st1v[4]; __shared__ int st0i[4], st1i[4];
    __shared__ float sav[4], sar[4];  __shared__ int sai[4];
    __shared__ float sg[4], sdp[4], sdn[4];

    const int i = blockIdx.x, t = threadIdx.x;
    const int l = t & 63, w = t >> 6;
    float* row = sq + (size_t)i * MSLOT;
    float v[8];
#pragma unroll
    for (int k = 0; k < 8; ++k) v[k] = row[t + k * 256];

    // --- row max ---
    float lmx = v[0];
#pragma unroll
    for (int k = 1; k < 8; ++k) lmx = fmaxf(lmx, v[k]);
#pragma unroll
    for (int off = 32; off; off >>= 1) lmx = fmaxf(lmx, __shfl_xor(lmx, off, 64));
    if (l == 0) swm[w] = lmx;
    __syncthreads();
    const float rm = fmaxf(fmaxf(swm[0], swm[1]), fmaxf(swm[2], swm[3]));

    // --- per-thread: sumexp, top2(raw), argmax(col-softmax) ---
    float ls = 0.0f;
#pragma unroll
    for (int k = 0; k < 8; ++k) ls += __expf(v[k] - rm);

    float v0 = -INFINITY, v1 = -INFINITY; int i0 = 0x7fffffff, i1 = 0x7fffffff;
#pragma unroll
    for (int k = 0; k < 8; ++k) {
        int idx = t + k * 256; float cv = v[k];
        if (cv > v0)      { v1 = v0; i1 = i0; v0 = cv; i0 = idx; }
        else if (cv > v1) { v1 = cv; i1 = idx; }
    }

    float av = -INFINITY, araw = 0.0f; int ai = 0x7fffffff;
#pragma unroll
    for (int k = 0; k < 8; ++k) {
        int idx = t + k * 256;
        float x = v[k] - colC[idx];
        if (x > av || (x == av && idx < ai)) { av = x; ai = idx; araw = v[k]; }
    }

    // wave reductions
#pragma unroll
    for (int off = 32; off; off >>= 1) ls += __shfl_xor(ls, off, 64);
#pragma unroll
    for (int off = 1; off < 64; off <<= 1) {
        float b0 = __shfl_xor(v0, off, 64), b1 = __shfl_xor(v1, off, 64);
        int  bi0 = __shfl_xor(i0, off, 64), bi1 = __shfl_xor(i1, off, 64);
        top2_merge(v0, i0, v1, i1, b0, bi0, b1, bi1);
    }
#pragma unroll
    for (int off = 1; off < 64; off <<= 1) {
        float ov = __shfl_xor(av, off, 64), oraw = __shfl_xor(araw, off, 64);
        int   oi = __shfl_xor(ai, off, 64);
        if (ov > av || (ov == av && oi < ai)) { av = ov; ai = oi; araw = oraw; }
    }
    if (l == 0) {
        sws[w] = ls;
        st0v[w] = v0; st0i[w] = i0; st1v[w] = v1; st1i[w] = i1;
        sav[w] = av; sai[w] = ai; sar[w] = araw;
    }
    __syncthreads();

    const float rs = (sws[0] + sws[1]) + (sws[2] + sws[3]);
    const float rsinv = 1.0f / rs;

    float T0 = -INFINITY, T1 = -INFINITY; int I0 = 0x7fffffff, I1 = 0x7fffffff;
#pragma unroll
    for (int ww = 0; ww < 4; ++ww)
        top2_merge(T0, I0, T1, I1, st0v[ww], st0i[ww], st1v[ww], st1i[ww]);

    float AV = -INFINITY, AR = 0.0f; int AI = 0x7fffffff;
#pragma unroll
    for (int ww = 0; ww < 4; ++ww) {
        if (sav[ww] > AV || (sav[ww] == AV && sai[ww] < AI)) { AV = sav[ww]; AI = sai[ww]; AR = sar[ww]; }
    }

    // --- losses ---
    float qv = out0[(size_t)i * (2 * D) + t];
    float pv = memory[(size_t)I0 * D + t];
    float nv = memory[(size_t)I1 * D + t];
    float dq = qv - pv;
    float g  = dq * dq;
    float dp = dq + 1e-6f;          dp *= dp;
    float dn = (qv - nv) + 1e-6f;   dn *= dn;
#pragma unroll
    for (int off = 32; off; off >>= 1) {
        g  += __shfl_xor(g, off, 64);
        dp += __shfl_xor(dp, off, 64);
        dn += __shfl_xor(dn, off, 64);
    }
    if (l == 0) { sg[w] = g; sdp[w] = dp; sdn[w] = dn; }
    __syncthreads();
    if (t == 0) {
        float gs  = (sg[0] + sg[1]) + (sg[2] + sg[3]);
        float dps = (sdp[0] + sdp[1]) + (sdp[2] + sdp[3]);
        float dns = (sdn[0] + sdn[1]) + (sdn[2] + sdn[3]);
        gpart[i] = gs;
        spart[i] = fmaxf(sqrtf(dps) - sqrtf(dns) + 1.0f, 0.0f);
        jstarA[i] = AI;
        wA[i] = __expf(AR - colM[AI]);
    }

    // --- softmax transforms (in-place for sq) ---
#pragma unroll
    for (int k = 0; k < 8; ++k) {
        int j = t + k * 256;
        row[j] = __expf(v[k] - colM[j]) * colSinv[j];
        sm[(size_t)i * MSLOT + j] = __expf(v[k] - rm) * rsinv;
    }
}

// ---------------------------------------------------------------- segment sum (atomic scatter)
__global__ __launch_bounds__(256) void k_scatter(const float* __restrict__ out0,
                                                 const int* __restrict__ jstarA,
                                                 const float* __restrict__ wA,
                                                 float* __restrict__ qupd)
{
    const int i = blockIdx.x, t = threadIdx.x;
    const int j = jstarA[i];
    const float wv = wA[i];
    unsafeAtomicAdd(&qupd[(size_t)j * D + t], wv * out0[(size_t)i * (2 * D) + t]);
}

// ---------------------------------------------------------------- updated memory
__global__ __launch_bounds__(256) void k_updmem(const float* __restrict__ qupd,
                                                const float* __restrict__ memory,
                                                float* __restrict__ out1)
{
    __shared__ float sbuf[4];
    const int j = blockIdx.x, t = threadIdx.x;
    float v = qupd[(size_t)j * D + t] + memory[(size_t)j * D + t];
    float ss = v * v;
#pragma unroll
    for (int off = 32; off; off >>= 1) ss += __shfl_xor(ss, off, 64);
    if ((t & 63) == 0) sbuf[t >> 6] = ss;
    __syncthreads();
    float tot = (sbuf[0] + sbuf[1]) + (sbuf[2] + sbuf[3]);
    float n = fmaxf(sqrtf(tot), 1e-12f);
    out1[(size_t)j * D + t] = v / n;
}

// ---------------------------------------------------------------- concat GEMM: out0 right = sfxm @ memory (f16 MFMA)
// A = out3 f32 [BS][2048] converted on the fly; B = memT f16 [256][2048] ([n][k]).
__global__ __launch_bounds__(256) void k_concat(const float* __restrict__ P,
                                                const f16* __restrict__ memT,
                                                float* __restrict__ out0)
{
    __shared__ __align__(16) f16 As[2][4096 / 2];   // [buf][64*32]
    __shared__ __align__(16) f16 Bs[2][8192];       // [buf][256*32]
    const int t = threadIdx.x;
    const int l = t & 63, w = t >> 6;
    const int lk = l >> 4, lm = l & 15;
    const int i0 = blockIdx.x * 64;

    const int ar = t >> 2, acm = t & 3;
    const int aslot = acm ^ ((ar >> 1) & 3);

    f32x4 acc[4][4] = {};
    float4 pa, pb;

    // prologue: stage k-step 0
    {
        const float4* ap = (const float4*)(P + (size_t)(i0 + ar) * MSLOT + acm * 8);
        pa = ap[0]; pb = ap[1];
#pragma unroll
        for (int c = 0; c < 4; ++c) {
            int s = c * 256 + t;
            int n = s >> 2, cc = s & 3;
            int scc = cc ^ ((n >> 1) & 3);
            lds_cp16(&Bs[0][s * 8], memT + (size_t)n * MSLOT + scc * 8);
        }
        f16x8 h;
        h[0] = (f16)pa.x; h[1] = (f16)pa.y; h[2] = (f16)pa.z; h[3] = (f16)pa.w;
        h[4] = (f16)pb.x; h[5] = (f16)pb.y; h[6] = (f16)pb.z; h[7] = (f16)pb.w;
        *(f16x8*)((char*)As[0] + ar * 64 + (aslot << 4)) = h;
        __syncthreads();
    }

    for (int ks = 0; ks < 64; ++ks) {
        const int cur = ks & 1, nxt = cur ^ 1;
        if (ks < 63) {
            const int k0 = (ks + 1) * 32;
            const float4* ap = (const float4*)(P + (size_t)(i0 + ar) * MSLOT + k0 + acm * 8);
            pa = ap[0]; pb = ap[1];
#pragma unroll
            for (int c = 0; c < 4; ++c) {
                int s = c * 256 + t;
                int n = s >> 2, cc = s & 3;
                int scc = cc ^ ((n >> 1) & 3);
                lds_cp16(&Bs[nxt][s * 8], memT + (size_t)n * MSLOT + k0 + scc * 8);
            }
        }
        // compute from cur
        f16x8 af[4], bf[4];
#pragma unroll
        for (int m = 0; m < 4; ++m) {
            int r = m * 16 + lm;
            int off = r * 64 + ((lk ^ ((r >> 1) & 3)) << 4);
            af[m] = *(const f16x8*)((const char*)As[cur] + off);
        }
#pragma unroll
        for (int n = 0; n < 4; ++n) {
            int r = w * 64 + n * 16 + lm;
            int off = r * 64 + ((lk ^ ((r >> 1) & 3)) << 4);
            bf[n] = *(const f16x8*)((const char*)Bs[cur] + off);
        }
#pragma unroll
        for (int m = 0; m < 4; ++m)
#pragma unroll
            for (int n = 0; n < 4; ++n)
                acc[m][n] = __builtin_amdgcn_mfma_f32_16x16x32_f16(af[m], bf[n], acc[m][n], 0, 0, 0);

        if (ks < 63) {
            f16x8 h;
            h[0] = (f16)pa.x; h[1] = (f16)pa.y; h[2] = (f16)pa.z; h[3] = (f16)pa.w;
            h[4] = (f16)pb.x; h[5] = (f16)pb.y; h[6] = (f16)pb.z; h[7] = (f16)pb.w;
            *(f16x8*)((char*)As[nxt] + ar * 64 + (aslot << 4)) = h;
        }
        __syncthreads();
    }

    // epilogue
#pragma unroll
    for (int m = 0; m < 4; ++m) {
        int row = i0 + m * 16 + lk * 4;
#pragma unroll
        for (int n = 0; n < 4; ++n) {
            int col = w * 64 + n * 16 + lm;
#pragma unroll
            for (int r = 0; r < 4; ++r)
                out0[(size_t)(row + r) * (2 * D) + D + col] = acc[m][n][r];
        }
    }
}

// ---------------------------------------------------------------- loss reduce
__global__ __launch_bounds__(256) void k_losses(const float* __restrict__ gpart,
                                                const float* __restrict__ spart,
                                                float* __restrict__ out45)
{
    __shared__ float sf[256];
    const int t = threadIdx.x;
    float g = 0.f, s = 0.f;
    for (int i = t; i < BS; i += 256) { g += gpart[i]; s += spart[i]; }
    sf[t] = g; __syncthreads();
    for (int off = 128; off; off >>= 1) { if (t < off) sf[t] += sf[t + off]; __syncthreads(); }
    float gt = sf[0]; __syncthreads();
    sf[t] = s; __syncthreads();
    for (int off = 128; off; off >>= 1) { if (t < off) sf[t] += sf[t + off]; __syncthreads(); }
    float st = sf[0];
    if (t == 0) {
        out45[0] = gt / (float)((size_t)BS * D);
        out45[1] = st / (float)BS;
    }
}

// ---------------------------------------------------------------- launcher
extern "C" void kernel_launch(void* const* d_in, const int* in_sizes, int n_in,
                              void* d_out, int out_size, void* d_ws, size_t ws_size,
                              hipStream_t stream)
{
    const float* query  = (const float*)d_in[0];
    const float* memory = (const float*)d_in[1];

    float* out  = (float*)d_out;
    float* out0 = out;                                   // update_query  [BS][2D]
    float* out1 = out0 + (size_t)BS * 2 * D;             // updated_memory[M][D]
    float* out2 = out1 + (size_t)MSLOT * D;              // sfx_score_query [BS][M]
    float* out3 = out2 + (size_t)BS * MSLOT;             // sfx_score_memory[BS][M]
    float* out45 = out3 + (size_t)BS * MSLOT;            // two scalars

    f16* qh   = (f16*)d_ws;                              // BS*D
    f16* ql   = qh + (size_t)BS * D;                     // BS*D
    f16* mh   = ql + (size_t)BS * D;                     // M*D
    f16* ml   = mh + (size_t)MSLOT * D;                  // M*D
    f16* memT = ml + (size_t)MSLOT * D;                  // D*M
    float* colpart = (float*)(memT + (size_t)D * MSLOT); // NCHUNK*M*2
    float* colM    = colpart + (size_t)NCHUNK * MSLOT * 2;
    float* colSinv = colM + MSLOT;
    float* colC    = colSinv + MSLOT;
    float* wA      = colC + MSLOT;                       // BS
    int*   jstarA  = (int*)(wA + BS);                    // BS
    float* gpart   = (float*)(jstarA + BS);              // BS
    float* spart   = gpart + BS;                         // BS
    float* qupd    = spart + BS;                         // M*D

    // 1) prep
    k_prepq<<<BS, 256, 0, stream>>>(query, out0, qh, ql);
    k_prepm<<<MSLOT, 256, 0, stream>>>(memory, mh, ml, memT);

    // 2) score GEMM (f16x2 x3 MFMA) + fused column partials
    k_score<<<dim3(MSLOT / 128, BS / 128), 256, 0, stream>>>(qh, ql, mh, ml, out2, colpart);

    // 3) column merge
    k_colmerge<<<MSLOT / 256, 256, 0, stream>>>(colpart, colM, colSinv, colC);

    // 4) fused row pass + softmax transforms
    k_rowtrans<<<BS, 256, 0, stream>>>(out2, out3, colM, colSinv, colC, out0, memory,
                                       jstarA, wA, gpart, spart);

    // 5) segment-sum memory update
    hipMemsetAsync(qupd, 0, (size_t)MSLOT * D * sizeof(float), stream);
    k_scatter<<<BS, 256, 0, stream>>>(out0, jstarA, wA, qupd);
    k_updmem<<<MSLOT, 256, 0, stream>>>(qupd, memory, out1);

    // 6) concat GEMM (f16 MFMA, double-buffered)
    k_concat<<<BS / 64, 256, 0, stream>>>(out3, memT, out0);

    // 7) losses
    k_losses<<<1, 256, 0, stream>>>(gpart, spart, out45);
}